// Round 11
// baseline (1166.636 us; speedup 1.0000x reference)
//
#include <hip/hip_runtime.h>
#include <hip/hip_bf16.h>

#define HID 128
#define SDIM 48
#define NSTEP 511
#define TFULL 512
#define ROWS 16
#define XHS 200            // fallback xh stride (u16)
#define HSTR 136           // h stride (u16): 272B, 16B-aligned
#define O1S 88
#define WENC_OFF 98304
#define BIAS_BYTE_OFF 208896
#define ENC_BYTE_OFF 211200                    // 256B-aligned
#define ENC_BYTES (4096ULL*TFULL*SDIM*2ULL)    // [b][512][48] bf16 = 201.3 MB

typedef unsigned short u16;
typedef unsigned int   u32;
typedef __attribute__((ext_vector_type(8))) short short8;
typedef __attribute__((ext_vector_type(4))) float f32x4;

__device__ __forceinline__ float frcp(float x)  { return __builtin_amdgcn_rcpf(x); }
__device__ __forceinline__ float sigm(float x)  { return frcp(1.0f + __expf(-x)); }
__device__ __forceinline__ float tanh_f(float x){ return 1.0f - 2.0f*frcp(1.0f + __expf(2.0f*x)); }
__device__ __forceinline__ u16 f2bf(float f) {
  __hip_bfloat16 h = __float2bfloat16(f);
  return *reinterpret_cast<u16*>(&h);
}
__device__ __forceinline__ u32 pk2(float a, float b) {
  return (u32)f2bf(a) | ((u32)f2bf(b) << 16);
}
__device__ __forceinline__ short8 pack8(float4 a, float4 b) {
  short8 r;
  r[0]=(short)f2bf(a.x); r[1]=(short)f2bf(a.y); r[2]=(short)f2bf(a.z); r[3]=(short)f2bf(a.w);
  r[4]=(short)f2bf(b.x); r[5]=(short)f2bf(b.y); r[6]=(short)f2bf(b.z); r[7]=(short)f2bf(b.w);
  return r;
}

// hfirst=1 (pre path):  K = [0..127]=h, [128..175]=enc, [176]=flow(w_ih col0),
//                       [177]=bias (b_ih+b_hh, B supplies 1.0), [178..191]=0
// hfirst=0 (fallback):  K = [0..47]=enc, [48..175]=h, [176..191]=0 (flow via rank-1)
__global__ void setup_weights(const float* __restrict__ w_ih, const float* __restrict__ w_hh,
                              const float* __restrict__ b_ih, const float* __restrict__ b_hh,
                              const float* __restrict__ enc_w1, const float* __restrict__ enc_w2,
                              u16* __restrict__ frags, float* __restrict__ bias, int hfirst) {
  int stride = gridDim.x * blockDim.x;
  int i0 = blockIdx.x * blockDim.x + threadIdx.x;
  for (int idx = i0; idx < 32*6*64*8; idx += stride) {
    int j  = idx & 7;
    int l  = (idx >> 3) & 63;
    int kt = (idx >> 9) % 6;
    int mt = (idx >> 9) / 6;
    int gr = mt*16 + (l & 15);
    int k  = kt*32 + (l >> 4)*8 + j;
    float v = 0.f;
    if (hfirst) {
      if (k < HID)        v = w_hh[gr*HID + k];
      else if (k < 176)   v = w_ih[gr*49 + 1 + (k - HID)];
      else if (k == 176)  v = w_ih[gr*49 + 0];             // flow column
      else if (k == 177)  v = b_ih[gr] + b_hh[gr];         // bias column (B=1.0)
    } else {
      if (k < 48)         v = w_ih[gr*49 + 1 + k];
      else if (k < 176)   v = w_hh[gr*HID + (k - 48)];
    }
    frags[idx] = f2bf(v);
  }
  for (int idx = i0; idx < 2*3*2*64*8; idx += stride) {
    int j   = idx & 7;
    int l   = (idx >> 3) & 63;
    int kt  = (idx >> 9) & 1;
    int mt  = (idx >> 10) % 3;
    int lyr = (idx >> 10) / 3;
    int row = mt*16 + (l & 15);
    int k   = kt*32 + (l >> 4)*8 + j;
    float v = 0.f;
    if (k < SDIM) v = (lyr ? enc_w2 : enc_w1)[row*SDIM + k];
    frags[WENC_OFF + idx] = f2bf(v);
  }
  for (int idx = i0; idx < 512; idx += stride)
    bias[idx] = b_ih[idx] + b_hh[idx];
}

// ---------------- kernel 2: precompute enc(b,t) for all t (massively parallel) --------
__global__ __launch_bounds__(256)
void enc_pre(const float* __restrict__ x_statics,
             const float* __restrict__ enc_b1, const float* __restrict__ enc_b2,
             const u16* __restrict__ frags, u16* __restrict__ enc_buf) {
  __shared__ __attribute__((aligned(16))) u16 s_o1[4][ROWS][O1S];
  const int tid = threadIdx.x;
  const int w  = tid >> 6;
  const int l  = tid & 63;
  const int lr = l & 15;
  const int lg = l >> 4;
  const int b     = blockIdx.x >> 3;
  const int chunk = blockIdx.x & 7;
  const int t = chunk*64 + w*16 + lr;

  short8 we1[3][2], we2[3][2];
  f32x4 a[3], e[3];
  #pragma unroll
  for (int mt = 0; mt < 3; ++mt) {
    #pragma unroll
    for (int kt = 0; kt < 2; ++kt) {
      we1[mt][kt] = *(const short8*)(frags + WENC_OFF + (((0*3 + mt)*2 + kt)*64 + l)*8);
      we2[mt][kt] = *(const short8*)(frags + WENC_OFF + (((1*3 + mt)*2 + kt)*64 + l)*8);
    }
    a[mt] = *(const f32x4*)&enc_b1[mt*16 + lg*4];
    e[mt] = *(const f32x4*)&enc_b2[mt*16 + lg*4];
  }

  *(unsigned long long*)&s_o1[w][l & 15][48 + (l >> 4)*4] = 0ULL;

  const float* xbase = x_statics + ((size_t)b*TFULL + t)*SDIM;
  float4 zf4 = make_float4(0.f,0.f,0.f,0.f);
  float4 c0a = *(const float4*)(xbase + lg*8);
  float4 c0b = *(const float4*)(xbase + lg*8 + 4);
  float4 c1a = zf4, c1b = zf4;
  if (lg < 2) {
    c1a = *(const float4*)(xbase + 32 + lg*8);
    c1b = *(const float4*)(xbase + 32 + lg*8 + 4);
  }
  short8 bx0 = pack8(c0a, c0b);
  short8 bx1 = pack8(c1a, c1b);

  #pragma unroll
  for (int mt = 0; mt < 3; ++mt) {
    a[mt] = __builtin_amdgcn_mfma_f32_16x16x32_bf16(we1[mt][0], bx0, a[mt], 0, 0, 0);
    a[mt] = __builtin_amdgcn_mfma_f32_16x16x32_bf16(we1[mt][1], bx1, a[mt], 0, 0, 0);
  }
  #pragma unroll
  for (int mt = 0; mt < 3; ++mt) {
    u32 lo = pk2(fmaxf(a[mt][0],0.f), fmaxf(a[mt][1],0.f));
    u32 hi = pk2(fmaxf(a[mt][2],0.f), fmaxf(a[mt][3],0.f));
    *(uint2*)&s_o1[w][lr][mt*16 + lg*4] = make_uint2(lo, hi);
  }
  asm volatile("s_waitcnt lgkmcnt(0)" ::: "memory");
  __builtin_amdgcn_sched_barrier(0);
  short8 bo0 = *(const short8*)&s_o1[w][lr][lg*8];
  short8 bo1 = *(const short8*)&s_o1[w][lr][32 + lg*8];
  #pragma unroll
  for (int mt = 0; mt < 3; ++mt) {
    e[mt] = __builtin_amdgcn_mfma_f32_16x16x32_bf16(we2[mt][0], bo0, e[mt], 0, 0, 0);
    e[mt] = __builtin_amdgcn_mfma_f32_16x16x32_bf16(we2[mt][1], bo1, e[mt], 0, 0, 0);
  }
  if (t < NSTEP) {
    u16* dst = enc_buf + ((size_t)b*TFULL + t)*SDIM;
    #pragma unroll
    for (int mt = 0; mt < 3; ++mt)
      *(uint2*)(dst + mt*16 + lg*4) = make_uint2(pk2(e[mt][0], e[mt][1]), pk2(e[mt][2], e[mt][3]));
  }
}

// ---------------- kernel 3: LSTM loop, DUAL independent chains per wave --------------
// 256 blocks x 512 threads (8 waves, 2/SIMD). Chain A = rows 0..7, chain B = rows
// 8..15; both share the same weight registers (A-operands). B-fragments row-duplicate
// (lane reads row lr&7 resp. 8+(lr&7)); duplicated output cols are don't-cares. Lane
// runs the cell on chain A if lr<8 else chain B -> cell work per lane unchanged.
// Bias and flow enter via K columns 177/176 (B supplies 1.0 / bf16(flow)).
__global__ __launch_bounds__(512, 2)
void lstm_dual(const float* __restrict__ y_flow,
               const int* __restrict__ twin_p,
               const float* __restrict__ out_w, const float* __restrict__ out_b,
               const u16* __restrict__ frags,
               const u16* __restrict__ enc_buf,
               float* __restrict__ out) {
  __shared__ __attribute__((aligned(16))) u16   s_h[2][ROWS][HSTR];
  __shared__ __attribute__((aligned(16))) float s_pp[2][8][ROWS];

  const int tid = threadIdx.x;
  const int blk = blockIdx.x;
  const int w  = tid >> 6;
  const int l  = tid & 63;
  const int lr = l & 15;
  const int lg = l >> 4;
  const int rA = lr & 7;          // chain-A source row
  const size_t b0 = (size_t)blk * ROWS;

  // shared weight fragments (96 VGPR) — used by BOTH chains
  short8 wf[4][6];
  #pragma unroll
  for (int q = 0; q < 4; ++q)
    #pragma unroll
    for (int kt = 0; kt < 6; ++kt)
      wf[q][kt] = *(const short8*)(frags + (((w + 8*q)*6 + kt)*64 + l)*8);

  float owv[4];
  #pragma unroll
  for (int r = 0; r < 4; ++r) owv[r] = out_w[w*16 + lg*4 + r];
  const float ob  = out_b[0];
  const int   twc = twin_p[0] - 1;   // teacher iff t < twc

  const u16*   erowA = enc_buf + (size_t)(b0 + rA)*TFULL*SDIM;
  const u16*   erowB = enc_buf + (size_t)(b0 + 8 + rA)*TFULL*SDIM;
  const float* yrowA = y_flow  + (size_t)(b0 + rA)*TFULL;
  const float* yrowB = y_flow  + (size_t)(b0 + 8 + rA)*TFULL;

  // prefetch enc(0) for both chains
  short8 eA0 = *(const short8*)(erowA + lg*8);          // enc cols 0..31
  short8 eA1 = *(const short8*)(erowB + lg*8);
  short8 eB0 = {}, eB1 = {};
  if (lg < 2) {
    eB0 = *(const short8*)(erowA + 32 + lg*8);          // enc cols 32..47
    eB1 = *(const short8*)(erowB + 32 + lg*8);
  }

  for (int i = tid; i < 2*ROWS*HSTR; i += 512) ((u16*)s_h)[i] = 0;
  for (int i = tid; i < 2*8*ROWS;   i += 512) ((float*)s_pp)[i] = 0.f;
  float c_reg[4] = {0.f, 0.f, 0.f, 0.f};
  __syncthreads();

  for (int st = 0; st < NSTEP; ++st) {
    const int p  = st & 1;
    const int p2 = p ^ 1;

    // teacher flow (early issue; L1-resident after first wave)
    float tfA = 0.f, tfB = 0.f;
    if (st < twc) { tfA = yrowA[st]; tfB = yrowB[st]; }

    // h fragments for both chains (row-duplicated reads; 2-way broadcast = free)
    short8 bhA[6], bhB[6];
    #pragma unroll
    for (int kt = 0; kt < 4; ++kt) {
      bhA[kt] = *(const short8*)&s_h[p][rA][kt*32 + lg*8];
      bhB[kt] = *(const short8*)&s_h[p][8 + rA][kt*32 + lg*8];
    }
    bhA[4] = eA0;
    bhB[4] = eA1;

    // pred(st-1) for both source rows (broadcast LDS reads)
    float pA = 0.f, pB = 0.f;
    #pragma unroll
    for (int ww = 0; ww < 8; ++ww) {
      pA += s_pp[p][ww][rA];
      pB += s_pp[p][ww][8 + rA];
    }
    float predA = pA + ob, predB = pB + ob;
    if (st == 0) { predA = 0.f; predB = 0.f; }
    if (st > 0 && l < 16 && (l >> 1) == w)
      out[(b0 + l)*NSTEP + (st - 1)] = (l < 8) ? predA : predB;

    const float flowA = (st < twc) ? tfA : predA;
    const float flowB = (st < twc) ? tfB : predB;

    // kt5 fragments: enc 32..47 (lg<2) + flow/bias columns (lg==2)
    short8 b5A = eB0, b5B = eB1;
    if (lg == 2) {
      b5A[0] = (short)f2bf(flowA); b5A[1] = (short)0x3F80;   // bf16 1.0
      b5B[0] = (short)f2bf(flowB); b5B[1] = (short)0x3F80;
    }
    bhA[5] = b5A;
    bhB[5] = b5B;

    // prefetch enc(st+1) — overlaps the MFMA/cell below
    const int tt = (st + 1 < NSTEP) ? (st + 1) : (NSTEP - 1);
    eA0 = *(const short8*)(erowA + (size_t)tt*SDIM + lg*8);
    eA1 = *(const short8*)(erowB + (size_t)tt*SDIM + lg*8);
    eB0 = (short8){}; eB1 = (short8){};
    if (lg < 2) {
      eB0 = *(const short8*)(erowA + (size_t)tt*SDIM + 32 + lg*8);
      eB1 = *(const short8*)(erowB + (size_t)tt*SDIM + 32 + lg*8);
    }

    // two independent 6-deep MFMA chains — interleaved, latency mutually hidden
    f32x4 aA[4], aB[4];
    #pragma unroll
    for (int q = 0; q < 4; ++q) { aA[q] = (f32x4){0,0,0,0}; aB[q] = (f32x4){0,0,0,0}; }
    #pragma unroll
    for (int kt = 0; kt < 6; ++kt)
      #pragma unroll
      for (int q = 0; q < 4; ++q) {
        aA[q] = __builtin_amdgcn_mfma_f32_16x16x32_bf16(wf[q][kt], bhA[kt], aA[q], 0, 0, 0);
        aB[q] = __builtin_amdgcn_mfma_f32_16x16x32_bf16(wf[q][kt], bhB[kt], aB[q], 0, 0, 0);
      }

    // cell: lane uses chain A if lr<8 (its row = lr), else chain B (row = lr)
    const bool isA = (lr < 8);
    f32x4 G[4];
    #pragma unroll
    for (int q = 0; q < 4; ++q) G[q] = isA ? aA[q] : aB[q];

    float hv[4];
    float hsum = 0.f;
    #pragma unroll
    for (int r = 0; r < 4; ++r) {
      float iv = sigm(G[0][r]);
      float fv = sigm(G[1][r]);
      float gv = tanh_f(G[2][r]);
      float ov = sigm(G[3][r]);
      float c  = fv*c_reg[r] + iv*gv;
      c_reg[r] = c;
      hv[r] = ov*tanh_f(c);
      hsum += hv[r]*owv[r];
    }
    *(uint2*)&s_h[p2][lr][w*16 + lg*4] = make_uint2(pk2(hv[0], hv[1]), pk2(hv[2], hv[3]));
    hsum += __shfl_xor(hsum, 16);
    hsum += __shfl_xor(hsum, 32);
    if (l < 16) s_pp[p2][w][l] = hsum;
    __syncthreads();                     // the ONE barrier
  }

  // epilogue: pred(NSTEP-1)
  const int pe = NSTEP & 1;
  float pA = 0.f, pB = 0.f;
  #pragma unroll
  for (int ww = 0; ww < 8; ++ww) {
    pA += s_pp[pe][ww][rA];
    pB += s_pp[pe][ww][8 + rA];
  }
  if (l < 16 && (l >> 1) == w)
    out[(b0 + l)*NSTEP + (NSTEP - 1)] = ((l < 8) ? pA : pB) + ob;
}

// ---------------- fallback: R5 kernel verbatim (wave-7 inline encoder) ---------------
__global__ __launch_bounds__(512, 2)
void lstm_fb(const float* __restrict__ y_flow,
             const float* __restrict__ x_statics,
             const int* __restrict__ twin_p,
             const float* __restrict__ enc_b1, const float* __restrict__ enc_b2,
             const float* __restrict__ out_w, const float* __restrict__ out_b,
             const float* __restrict__ w_ih,
             const u16* __restrict__ frags, const float* __restrict__ bias,
             float* __restrict__ out) {
  __shared__ __attribute__((aligned(16))) u16   s_xh[2][ROWS][XHS];
  __shared__ __attribute__((aligned(16))) u16   s_o1[ROWS][O1S];
  __shared__ __attribute__((aligned(16))) float s_pp[2][ROWS][8];
  __shared__ __attribute__((aligned(16))) float s_bias[512];
  __shared__ __attribute__((aligned(16))) float s_eb1[SDIM];
  __shared__ __attribute__((aligned(16))) float s_eb2[SDIM];

  const int tid = threadIdx.x;
  const int blk = blockIdx.x;
  const int w  = tid >> 6;
  const int l  = tid & 63;
  const int lr = l & 15;
  const int lg = l >> 4;
  const size_t b0 = (size_t)blk * ROWS;

  short8 wf[4][6];
  #pragma unroll
  for (int q = 0; q < 4; ++q)
    #pragma unroll
    for (int kt = 0; kt < 6; ++kt)
      wf[q][kt] = *(const short8*)(frags + (((w + 8*q)*6 + kt)*64 + l)*8);

  float wfl[4][4];
  #pragma unroll
  for (int q = 0; q < 4; ++q)
    #pragma unroll
    for (int r = 0; r < 4; ++r)
      wfl[q][r] = w_ih[((w + 8*q)*16 + lg*4 + r)*49];

  short8 we1[3][2], we2[3][2];
  if (w == 7) {
    #pragma unroll
    for (int mt = 0; mt < 3; ++mt)
      #pragma unroll
      for (int kt = 0; kt < 2; ++kt) {
        we1[mt][kt] = *(const short8*)(frags + WENC_OFF + (((0*3 + mt)*2 + kt)*64 + l)*8);
        we2[mt][kt] = *(const short8*)(frags + WENC_OFF + (((1*3 + mt)*2 + kt)*64 + l)*8);
      }
  }

  float owv[4];
  #pragma unroll
  for (int r = 0; r < 4; ++r) owv[r] = out_w[w*16 + lg*4 + r];
  const float ob  = out_b[0];
  const int   twc = twin_p[0] - 1;

  for (int i = tid; i < 2*ROWS*XHS; i += 512) ((u16*)s_xh)[i] = 0;
  for (int i = tid; i < ROWS*O1S;  i += 512) ((u16*)s_o1)[i] = 0;
  for (int i = tid; i < 2*ROWS*8;  i += 512) ((float*)s_pp)[i] = 0.f;
  s_bias[tid] = bias[tid];
  if (tid < SDIM) { s_eb1[tid] = enc_b1[tid]; s_eb2[tid] = enc_b2[tid]; }
  __syncthreads();

  const float* xrow = x_statics + (size_t)(b0 + lr)*TFULL*SDIM;
  const float* yrow = y_flow    + (size_t)(b0 + lr)*TFULL;

  auto enc_step = [&](short8 bx0, short8 bx1, int pp) {
    f32x4 a[3];
    #pragma unroll
    for (int mt = 0; mt < 3; ++mt) a[mt] = *(const f32x4*)&s_eb1[mt*16 + lg*4];
    #pragma unroll
    for (int mt = 0; mt < 3; ++mt) {
      a[mt] = __builtin_amdgcn_mfma_f32_16x16x32_bf16(we1[mt][0], bx0, a[mt], 0, 0, 0);
      a[mt] = __builtin_amdgcn_mfma_f32_16x16x32_bf16(we1[mt][1], bx1, a[mt], 0, 0, 0);
    }
    #pragma unroll
    for (int mt = 0; mt < 3; ++mt) {
      *(u32*)&s_o1[lr][mt*16 + lg*4]     = pk2(fmaxf(a[mt][0],0.f), fmaxf(a[mt][1],0.f));
      *(u32*)&s_o1[lr][mt*16 + lg*4 + 2] = pk2(fmaxf(a[mt][2],0.f), fmaxf(a[mt][3],0.f));
    }
    asm volatile("s_waitcnt lgkmcnt(0)" ::: "memory");
    __builtin_amdgcn_sched_barrier(0);
    short8 bo0 = *(const short8*)&s_o1[lr][lg*8];
    short8 bo1 = *(const short8*)&s_o1[lr][32 + lg*8];
    f32x4 e[3];
    #pragma unroll
    for (int mt = 0; mt < 3; ++mt) e[mt] = *(const f32x4*)&s_eb2[mt*16 + lg*4];
    #pragma unroll
    for (int mt = 0; mt < 3; ++mt) {
      e[mt] = __builtin_amdgcn_mfma_f32_16x16x32_bf16(we2[mt][0], bo0, e[mt], 0, 0, 0);
      e[mt] = __builtin_amdgcn_mfma_f32_16x16x32_bf16(we2[mt][1], bo1, e[mt], 0, 0, 0);
    }
    #pragma unroll
    for (int mt = 0; mt < 3; ++mt) {
      *(u32*)&s_xh[pp][lr][mt*16 + lg*4]     = pk2(e[mt][0], e[mt][1]);
      *(u32*)&s_xh[pp][lr][mt*16 + lg*4 + 2] = pk2(e[mt][2], e[mt][3]);
    }
  };
  auto load_xs = [&](int t, float4& a0, float4& b0_, float4& a1, float4& b1_) {
    a0 = *(const float4*)(xrow + (size_t)t*SDIM + lg*8);
    b0_= *(const float4*)(xrow + (size_t)t*SDIM + lg*8 + 4);
    if (lg < 2) {
      a1 = *(const float4*)(xrow + (size_t)t*SDIM + 32 + lg*8);
      b1_= *(const float4*)(xrow + (size_t)t*SDIM + 32 + lg*8 + 4);
    }
  };

  float4 zf4 = make_float4(0.f, 0.f, 0.f, 0.f);
  float4 xn0a = zf4, xn0b = zf4, xn1a = zf4, xn1b = zf4;
  if (w == 7) {
    float4 c0a = zf4, c0b = zf4, c1a = zf4, c1b = zf4;
    load_xs(0, c0a, c0b, c1a, c1b);
    enc_step(pack8(c0a, c0b), pack8(c1a, c1b), 0);
    load_xs(1, xn0a, xn0b, xn1a, xn1b);
  }
  float c_reg[4] = {0.f, 0.f, 0.f, 0.f};
  __syncthreads();

  for (int st = 0; st < NSTEP; ++st) {
    const int p  = st & 1;
    const int p2 = p ^ 1;

    short8 bh[6];
    #pragma unroll
    for (int kt = 0; kt < 6; ++kt)
      bh[kt] = *(const short8*)&s_xh[p][lr][kt*32 + lg*8];

    f32x4 acc[4];
    #pragma unroll
    for (int q = 0; q < 4; ++q) acc[q] = *(const f32x4*)&s_bias[(w + 8*q)*16 + lg*4];
    #pragma unroll
    for (int kt = 0; kt < 6; ++kt)
      #pragma unroll
      for (int q = 0; q < 4; ++q)
        acc[q] = __builtin_amdgcn_mfma_f32_16x16x32_bf16(wf[q][kt], bh[kt], acc[q], 0, 0, 0);

    f32x4 pa = *(const f32x4*)&s_pp[p][lr][0];
    f32x4 pb = *(const f32x4*)&s_pp[p][lr][4];
    float pp_s = ((pa[0]+pa[1]) + (pa[2]+pa[3])) + ((pb[0]+pb[1]) + (pb[2]+pb[3]));
    float pred_prev = pp_s + ob;
    if (st == 0) pred_prev = 0.f;
    if (st > 0 && l < 16 && (l >> 1) == w)
      out[(b0 + l)*NSTEP + (st - 1)] = pred_prev;

    float tf = 0.f;
    if (st < twc) tf = yrow[st];
    const float flow = (st < twc) ? tf : pred_prev;

    if (w == 7) {
      short8 bx0 = pack8(xn0a, xn0b);
      short8 bx1 = pack8(xn1a, xn1b);
      const int tt = (st + 2 < TFULL) ? (st + 2) : (TFULL - 1);
      load_xs(tt, xn0a, xn0b, xn1a, xn1b);
      __builtin_amdgcn_s_setprio(1);
      enc_step(bx0, bx1, p2);
      __builtin_amdgcn_s_setprio(0);
    }

    float hv[4];
    float hsum = 0.f;
    #pragma unroll
    for (int r = 0; r < 4; ++r) {
      float g_i = acc[0][r] + wfl[0][r]*flow;
      float g_f = acc[1][r] + wfl[1][r]*flow;
      float g_g = acc[2][r] + wfl[2][r]*flow;
      float g_o = acc[3][r] + wfl[3][r]*flow;
      float iv = sigm(g_i);
      float fv = sigm(g_f);
      float gv = tanh_f(g_g);
      float ov = sigm(g_o);
      float c  = fv*c_reg[r] + iv*gv;
      c_reg[r] = c;
      hv[r] = ov*tanh_f(c);
      hsum += hv[r]*owv[r];
    }
    *(u32*)&s_xh[p2][lr][48 + w*16 + lg*4]     = pk2(hv[0], hv[1]);
    *(u32*)&s_xh[p2][lr][48 + w*16 + lg*4 + 2] = pk2(hv[2], hv[3]);
    hsum += __shfl_xor(hsum, 16);
    hsum += __shfl_xor(hsum, 32);
    if (l < 16) s_pp[p2][l][w] = hsum;
    __syncthreads();
  }

  f32x4 pa = *(const f32x4*)&s_pp[NSTEP & 1][lr][0];
  f32x4 pb = *(const f32x4*)&s_pp[NSTEP & 1][lr][4];
  float pp_s = ((pa[0]+pa[1]) + (pa[2]+pa[3])) + ((pb[0]+pb[1]) + (pb[2]+pb[3]));
  if (l < 16 && (l >> 1) == w)
    out[(b0 + l)*NSTEP + (NSTEP - 1)] = pp_s + ob;
}

extern "C" void kernel_launch(void* const* d_in, const int* in_sizes, int n_in,
                              void* d_out, int out_size, void* d_ws, size_t ws_size,
                              hipStream_t stream) {
  const float* y_flow    = (const float*)d_in[0];
  const float* x_statics = (const float*)d_in[1];
  const int*   twin      = (const int*)  d_in[2];
  const float* enc_w1    = (const float*)d_in[3];
  const float* enc_b1    = (const float*)d_in[4];
  const float* enc_w2    = (const float*)d_in[5];
  const float* enc_b2    = (const float*)d_in[6];
  const float* w_ih      = (const float*)d_in[7];
  const float* w_hh      = (const float*)d_in[8];
  const float* b_ih      = (const float*)d_in[9];
  const float* b_hh      = (const float*)d_in[10];
  const float* out_w     = (const float*)d_in[11];
  const float* out_b     = (const float*)d_in[12];
  float* out = (float*)d_out;

  char* ws = (char*)d_ws;
  u16*   frags   = (u16*)ws;
  float* bias    = (float*)(ws + BIAS_BYTE_OFF);
  u16*   enc_buf = (u16*)(ws + ENC_BYTE_OFF);

  const int pre = (ws_size >= (size_t)ENC_BYTE_OFF + ENC_BYTES) ? 1 : 0;

  setup_weights<<<128, 256, 0, stream>>>(w_ih, w_hh, b_ih, b_hh, enc_w1, enc_w2,
                                         frags, bias, pre);
  if (pre) {
    enc_pre<<<4096*8, 256, 0, stream>>>(x_statics, enc_b1, enc_b2, frags, enc_buf);
    lstm_dual<<<256, 512, 0, stream>>>(y_flow, twin, out_w, out_b,
                                       frags, enc_buf, out);
  } else {
    lstm_fb<<<256, 512, 0, stream>>>(y_flow, x_statics, twin,
                                     enc_b1, enc_b2, out_w, out_b, w_ih,
                                     frags, bias, out);
  }
}

// Round 12
// 1029.939 us; speedup vs baseline: 1.1327x; 1.1327x over previous
//
#include <hip/hip_runtime.h>
#include <hip/hip_bf16.h>

#define HID 128
#define SDIM 48
#define NSTEP 511
#define TFULL 512
#define ROWS 16
#define XHS 200            // fallback xh stride (u16)
#define HSTR 136           // h stride (u16): 272B, 16B-aligned
#define O1S 88
#define WENC_OFF 98304
#define BIAS_BYTE_OFF 208896
#define ENC_BYTE_OFF 211200                    // 256B-aligned
#define ENC_BYTES (4096ULL*TFULL*SDIM*2ULL)    // [b][512][48] bf16 = 201.3 MB

typedef unsigned short u16;
typedef unsigned int   u32;
typedef __attribute__((ext_vector_type(8))) short short8;
typedef __attribute__((ext_vector_type(4))) float f32x4;
typedef __attribute__((ext_vector_type(4))) u32   u32x4;

__device__ __forceinline__ float frcp(float x)  { return __builtin_amdgcn_rcpf(x); }
__device__ __forceinline__ float sigm(float x)  { return frcp(1.0f + __expf(-x)); }
__device__ __forceinline__ float tanh_f(float x){ return 1.0f - 2.0f*frcp(1.0f + __expf(2.0f*x)); }
__device__ __forceinline__ u16 f2bf(float f) {
  __hip_bfloat16 h = __float2bfloat16(f);
  return *reinterpret_cast<u16*>(&h);
}
__device__ __forceinline__ u32 pk2(float a, float b) {
  return (u32)f2bf(a) | ((u32)f2bf(b) << 16);
}
// single-instruction packed f32->2xbf16 (RNE), gfx950
__device__ __forceinline__ u32 cvtpk(float lo, float hi) {
  u32 r;
  asm("v_cvt_pk_bf16_f32 %0, %1, %2" : "=v"(r) : "v"(lo), "v"(hi));
  return r;
}
__device__ __forceinline__ short8 pack8(float4 a, float4 b) {
  short8 r;
  r[0]=(short)f2bf(a.x); r[1]=(short)f2bf(a.y); r[2]=(short)f2bf(a.z); r[3]=(short)f2bf(a.w);
  r[4]=(short)f2bf(b.x); r[5]=(short)f2bf(b.y); r[6]=(short)f2bf(b.z); r[7]=(short)f2bf(b.w);
  return r;
}

// hfirst=1 (pre path):  K = [0..127]=h, [128..175]=enc, [176]=flow(w_ih col0),
//                       [177]=bias (b_ih+b_hh, B supplies 1.0), [178..191]=0
// hfirst=0 (fallback):  K = [0..47]=enc, [48..175]=h, [176..191]=0 (flow via rank-1)
__global__ void setup_weights(const float* __restrict__ w_ih, const float* __restrict__ w_hh,
                              const float* __restrict__ b_ih, const float* __restrict__ b_hh,
                              const float* __restrict__ enc_w1, const float* __restrict__ enc_w2,
                              u16* __restrict__ frags, float* __restrict__ bias, int hfirst) {
  int stride = gridDim.x * blockDim.x;
  int i0 = blockIdx.x * blockDim.x + threadIdx.x;
  for (int idx = i0; idx < 32*6*64*8; idx += stride) {
    int j  = idx & 7;
    int l  = (idx >> 3) & 63;
    int kt = (idx >> 9) % 6;
    int mt = (idx >> 9) / 6;
    int gr = mt*16 + (l & 15);
    int k  = kt*32 + (l >> 4)*8 + j;
    float v = 0.f;
    if (hfirst) {
      if (k < HID)        v = w_hh[gr*HID + k];
      else if (k < 176)   v = w_ih[gr*49 + 1 + (k - HID)];
      else if (k == 176)  v = w_ih[gr*49 + 0];             // flow column
      else if (k == 177)  v = b_ih[gr] + b_hh[gr];         // bias column (B=1.0)
    } else {
      if (k < 48)         v = w_ih[gr*49 + 1 + k];
      else if (k < 176)   v = w_hh[gr*HID + (k - 48)];
    }
    frags[idx] = f2bf(v);
  }
  for (int idx = i0; idx < 2*3*2*64*8; idx += stride) {
    int j   = idx & 7;
    int l   = (idx >> 3) & 63;
    int kt  = (idx >> 9) & 1;
    int mt  = (idx >> 10) % 3;
    int lyr = (idx >> 10) / 3;
    int row = mt*16 + (l & 15);
    int k   = kt*32 + (l >> 4)*8 + j;
    float v = 0.f;
    if (k < SDIM) v = (lyr ? enc_w2 : enc_w1)[row*SDIM + k];
    frags[WENC_OFF + idx] = f2bf(v);
  }
  for (int idx = i0; idx < 512; idx += stride)
    bias[idx] = b_ih[idx] + b_hh[idx];
}

// ---------------- kernel 2: precompute enc(b,t) for all t (massively parallel) --------
__global__ __launch_bounds__(256)
void enc_pre(const float* __restrict__ x_statics,
             const float* __restrict__ enc_b1, const float* __restrict__ enc_b2,
             const u16* __restrict__ frags, u16* __restrict__ enc_buf) {
  __shared__ __attribute__((aligned(16))) u16 s_o1[4][ROWS][O1S];
  const int tid = threadIdx.x;
  const int w  = tid >> 6;
  const int l  = tid & 63;
  const int lr = l & 15;
  const int lg = l >> 4;
  const int b     = blockIdx.x >> 3;
  const int chunk = blockIdx.x & 7;
  const int t = chunk*64 + w*16 + lr;

  short8 we1[3][2], we2[3][2];
  f32x4 a[3], e[3];
  #pragma unroll
  for (int mt = 0; mt < 3; ++mt) {
    #pragma unroll
    for (int kt = 0; kt < 2; ++kt) {
      we1[mt][kt] = *(const short8*)(frags + WENC_OFF + (((0*3 + mt)*2 + kt)*64 + l)*8);
      we2[mt][kt] = *(const short8*)(frags + WENC_OFF + (((1*3 + mt)*2 + kt)*64 + l)*8);
    }
    a[mt] = *(const f32x4*)&enc_b1[mt*16 + lg*4];
    e[mt] = *(const f32x4*)&enc_b2[mt*16 + lg*4];
  }

  *(unsigned long long*)&s_o1[w][l & 15][48 + (l >> 4)*4] = 0ULL;

  const float* xbase = x_statics + ((size_t)b*TFULL + t)*SDIM;
  float4 zf4 = make_float4(0.f,0.f,0.f,0.f);
  float4 c0a = *(const float4*)(xbase + lg*8);
  float4 c0b = *(const float4*)(xbase + lg*8 + 4);
  float4 c1a = zf4, c1b = zf4;
  if (lg < 2) {
    c1a = *(const float4*)(xbase + 32 + lg*8);
    c1b = *(const float4*)(xbase + 32 + lg*8 + 4);
  }
  short8 bx0 = pack8(c0a, c0b);
  short8 bx1 = pack8(c1a, c1b);

  #pragma unroll
  for (int mt = 0; mt < 3; ++mt) {
    a[mt] = __builtin_amdgcn_mfma_f32_16x16x32_bf16(we1[mt][0], bx0, a[mt], 0, 0, 0);
    a[mt] = __builtin_amdgcn_mfma_f32_16x16x32_bf16(we1[mt][1], bx1, a[mt], 0, 0, 0);
  }
  #pragma unroll
  for (int mt = 0; mt < 3; ++mt) {
    u32 lo = pk2(fmaxf(a[mt][0],0.f), fmaxf(a[mt][1],0.f));
    u32 hi = pk2(fmaxf(a[mt][2],0.f), fmaxf(a[mt][3],0.f));
    *(uint2*)&s_o1[w][lr][mt*16 + lg*4] = make_uint2(lo, hi);
  }
  asm volatile("s_waitcnt lgkmcnt(0)" ::: "memory");
  __builtin_amdgcn_sched_barrier(0);
  short8 bo0 = *(const short8*)&s_o1[w][lr][lg*8];
  short8 bo1 = *(const short8*)&s_o1[w][lr][32 + lg*8];
  #pragma unroll
  for (int mt = 0; mt < 3; ++mt) {
    e[mt] = __builtin_amdgcn_mfma_f32_16x16x32_bf16(we2[mt][0], bo0, e[mt], 0, 0, 0);
    e[mt] = __builtin_amdgcn_mfma_f32_16x16x32_bf16(we2[mt][1], bo1, e[mt], 0, 0, 0);
  }
  if (t < NSTEP) {
    u16* dst = enc_buf + ((size_t)b*TFULL + t)*SDIM;
    #pragma unroll
    for (int mt = 0; mt < 3; ++mt)
      *(uint2*)(dst + mt*16 + lg*4) = make_uint2(pk2(e[mt][0], e[mt][1]), pk2(e[mt][2], e[mt][3]));
  }
}

// ---------------- kernel 3: LSTM loop, instruction-diet version ----------------------
// 256 blocks x 512 threads (8 waves, 2/SIMD). Wave w owns gate M-tiles
// {w,w+8,w+16,w+24}; i/f/g/o in-lane. Bias and flow enter through K columns
// 177/176 (B supplies 1.0 / bf16(flow)) -> no acc-init movs, no flow fmas.
// #pragma unroll 2 makes the ping-pong index static -> LDS addrs fold to
// base + ds-offset immediates. h pack via single v_cvt_pk_bf16_f32.
__global__ __launch_bounds__(512, 2)
void lstm_pre(const float* __restrict__ y_flow,
              const int* __restrict__ twin_p,
              const float* __restrict__ out_w, const float* __restrict__ out_b,
              const u16* __restrict__ frags,
              const u16* __restrict__ enc_buf,
              float* __restrict__ out) {
  __shared__ __attribute__((aligned(16))) u16   s_h[2][ROWS][HSTR];
  __shared__ __attribute__((aligned(16))) float s_pp[2][8][ROWS];

  const int tid = threadIdx.x;
  const int blk = blockIdx.x;
  const int w  = tid >> 6;
  const int l  = tid & 63;
  const int lr = l & 15;
  const int lg = l >> 4;
  const size_t b0 = (size_t)blk * ROWS;

  short8 wf[4][6];
  #pragma unroll
  for (int q = 0; q < 4; ++q)
    #pragma unroll
    for (int kt = 0; kt < 6; ++kt)
      wf[q][kt] = *(const short8*)(frags + (((w + 8*q)*6 + kt)*64 + l)*8);

  float owv[4];
  #pragma unroll
  for (int r = 0; r < 4; ++r) owv[r] = out_w[w*16 + lg*4 + r];
  const float ob  = out_b[0];
  const int   twc = twin_p[0] - 1;   // teacher iff t < twc

  const u16*   erow = enc_buf + (size_t)(b0 + lr)*TFULL*SDIM;
  const float* yrow = y_flow  + (size_t)(b0 + lr)*TFULL;

  // prefetch enc(0)
  short8 encA = *(const short8*)(erow + lg*8);
  short8 encB = {};
  if (lg < 2) encB = *(const short8*)(erow + 32 + lg*8);

  for (int i = tid; i < 2*ROWS*HSTR; i += 512) ((u16*)s_h)[i] = 0;
  for (int i = tid; i < 2*8*ROWS;   i += 512) ((float*)s_pp)[i] = 0.f;
  float c_reg[4] = {0.f, 0.f, 0.f, 0.f};
  __syncthreads();

  const f32x4 z4 = {0.f, 0.f, 0.f, 0.f};   // hoisted zero C-operand

  #pragma unroll 2
  for (int st = 0; st < NSTEP; ++st) {
    const int p  = st & 1;
    const int p2 = p ^ 1;

    // issue next-step global loads FIRST — latency hides under this step
    const int tt = (st + 1) & 511;          // row 511 is garbage, never consumed
    short8 nA = *(const short8*)(erow + (size_t)tt*SDIM + lg*8);
    short8 nB = {};
    if (lg < 2) nB = *(const short8*)(erow + (size_t)tt*SDIM + 32 + lg*8);
    float tf = 0.f;
    if (st < twc) tf = yrow[st];

    // B fragments (static LDS offsets after unroll)
    short8 bh[6];
    #pragma unroll
    for (int kt = 0; kt < 4; ++kt)
      bh[kt] = *(const short8*)&s_h[p][lr][kt*32 + lg*8];
    bh[4] = encA;

    // pred(st-1): 8 conflict-free broadcast reads
    float pp01 = s_pp[p][0][lr] + s_pp[p][1][lr];
    float pp23 = s_pp[p][2][lr] + s_pp[p][3][lr];
    float pp45 = s_pp[p][4][lr] + s_pp[p][5][lr];
    float pp67 = s_pp[p][6][lr] + s_pp[p][7][lr];
    float pred_prev = ((pp01 + pp23) + (pp45 + pp67)) + ob;
    if (st == 0) pred_prev = 0.f;
    if (st > 0 && l < 16 && (l >> 1) == w)
      out[(b0 + l)*NSTEP + (st - 1)] = pred_prev;
    const float flow = (st < twc) ? tf : pred_prev;

    // kt5: enc 32..47 (lg<2); lg==2 word0 = {flow, 1.0} via one cvt_pk
    u32x4 bv = __builtin_bit_cast(u32x4, encB);
    u32 fw = cvtpk(flow, 1.0f);             // low=flow, high=bf16 1.0
    bv[0] = (lg == 2) ? fw : bv[0];
    bh[5] = __builtin_bit_cast(short8, bv);

    // gates: 6-deep MFMA chains, C starts from hoisted zero (no movs)
    f32x4 acc[4];
    #pragma unroll
    for (int q = 0; q < 4; ++q)
      acc[q] = __builtin_amdgcn_mfma_f32_16x16x32_bf16(wf[q][0], bh[0], z4, 0, 0, 0);
    #pragma unroll
    for (int kt = 1; kt < 6; ++kt)
      #pragma unroll
      for (int q = 0; q < 4; ++q)
        acc[q] = __builtin_amdgcn_mfma_f32_16x16x32_bf16(wf[q][kt], bh[kt], acc[q], 0, 0, 0);

    // LSTM cell (bias+flow already inside acc)
    float hv[4];
    float hsum = 0.f;
    #pragma unroll
    for (int r = 0; r < 4; ++r) {
      float iv = sigm(acc[0][r]);
      float fv = sigm(acc[1][r]);
      float gv = tanh_f(acc[2][r]);
      float ov = sigm(acc[3][r]);
      float c  = fv*c_reg[r] + iv*gv;
      c_reg[r] = c;
      hv[r] = ov*tanh_f(c);
      hsum += hv[r]*owv[r];
    }
    *(uint2*)&s_h[p2][lr][w*16 + lg*4] =
        make_uint2(cvtpk(hv[0], hv[1]), cvtpk(hv[2], hv[3]));
    hsum += __shfl_xor(hsum, 16);
    hsum += __shfl_xor(hsum, 32);
    if (l < 16) s_pp[p2][w][l] = hsum;

    encA = nA; encB = nB;
    __syncthreads();
  }

  // epilogue: pred(NSTEP-1); last step (510, p=0) wrote s_pp[1]
  const int pe = NSTEP & 1;
  float pp01 = s_pp[pe][0][lr] + s_pp[pe][1][lr];
  float pp23 = s_pp[pe][2][lr] + s_pp[pe][3][lr];
  float pp45 = s_pp[pe][4][lr] + s_pp[pe][5][lr];
  float pp67 = s_pp[pe][6][lr] + s_pp[pe][7][lr];
  if (l < 16 && (l >> 1) == w)
    out[(b0 + l)*NSTEP + (NSTEP - 1)] = ((pp01 + pp23) + (pp45 + pp67)) + ob;
}

// ---------------- fallback: R5 kernel verbatim (wave-7 inline encoder) ---------------
__global__ __launch_bounds__(512, 2)
void lstm_fb(const float* __restrict__ y_flow,
             const float* __restrict__ x_statics,
             const int* __restrict__ twin_p,
             const float* __restrict__ enc_b1, const float* __restrict__ enc_b2,
             const float* __restrict__ out_w, const float* __restrict__ out_b,
             const float* __restrict__ w_ih,
             const u16* __restrict__ frags, const float* __restrict__ bias,
             float* __restrict__ out) {
  __shared__ __attribute__((aligned(16))) u16   s_xh[2][ROWS][XHS];
  __shared__ __attribute__((aligned(16))) u16   s_o1[ROWS][O1S];
  __shared__ __attribute__((aligned(16))) float s_pp[2][ROWS][8];
  __shared__ __attribute__((aligned(16))) float s_bias[512];
  __shared__ __attribute__((aligned(16))) float s_eb1[SDIM];
  __shared__ __attribute__((aligned(16))) float s_eb2[SDIM];

  const int tid = threadIdx.x;
  const int blk = blockIdx.x;
  const int w  = tid >> 6;
  const int l  = tid & 63;
  const int lr = l & 15;
  const int lg = l >> 4;
  const size_t b0 = (size_t)blk * ROWS;

  short8 wf[4][6];
  #pragma unroll
  for (int q = 0; q < 4; ++q)
    #pragma unroll
    for (int kt = 0; kt < 6; ++kt)
      wf[q][kt] = *(const short8*)(frags + (((w + 8*q)*6 + kt)*64 + l)*8);

  float wfl[4][4];
  #pragma unroll
  for (int q = 0; q < 4; ++q)
    #pragma unroll
    for (int r = 0; r < 4; ++r)
      wfl[q][r] = w_ih[((w + 8*q)*16 + lg*4 + r)*49];

  short8 we1[3][2], we2[3][2];
  if (w == 7) {
    #pragma unroll
    for (int mt = 0; mt < 3; ++mt)
      #pragma unroll
      for (int kt = 0; kt < 2; ++kt) {
        we1[mt][kt] = *(const short8*)(frags + WENC_OFF + (((0*3 + mt)*2 + kt)*64 + l)*8);
        we2[mt][kt] = *(const short8*)(frags + WENC_OFF + (((1*3 + mt)*2 + kt)*64 + l)*8);
      }
  }

  float owv[4];
  #pragma unroll
  for (int r = 0; r < 4; ++r) owv[r] = out_w[w*16 + lg*4 + r];
  const float ob  = out_b[0];
  const int   twc = twin_p[0] - 1;

  for (int i = tid; i < 2*ROWS*XHS; i += 512) ((u16*)s_xh)[i] = 0;
  for (int i = tid; i < ROWS*O1S;  i += 512) ((u16*)s_o1)[i] = 0;
  for (int i = tid; i < 2*ROWS*8;  i += 512) ((float*)s_pp)[i] = 0.f;
  s_bias[tid] = bias[tid];
  if (tid < SDIM) { s_eb1[tid] = enc_b1[tid]; s_eb2[tid] = enc_b2[tid]; }
  __syncthreads();

  const float* xrow = x_statics + (size_t)(b0 + lr)*TFULL*SDIM;
  const float* yrow = y_flow    + (size_t)(b0 + lr)*TFULL;

  auto enc_step = [&](short8 bx0, short8 bx1, int pp) {
    f32x4 a[3];
    #pragma unroll
    for (int mt = 0; mt < 3; ++mt) a[mt] = *(const f32x4*)&s_eb1[mt*16 + lg*4];
    #pragma unroll
    for (int mt = 0; mt < 3; ++mt) {
      a[mt] = __builtin_amdgcn_mfma_f32_16x16x32_bf16(we1[mt][0], bx0, a[mt], 0, 0, 0);
      a[mt] = __builtin_amdgcn_mfma_f32_16x16x32_bf16(we1[mt][1], bx1, a[mt], 0, 0, 0);
    }
    #pragma unroll
    for (int mt = 0; mt < 3; ++mt) {
      *(u32*)&s_o1[lr][mt*16 + lg*4]     = pk2(fmaxf(a[mt][0],0.f), fmaxf(a[mt][1],0.f));
      *(u32*)&s_o1[lr][mt*16 + lg*4 + 2] = pk2(fmaxf(a[mt][2],0.f), fmaxf(a[mt][3],0.f));
    }
    asm volatile("s_waitcnt lgkmcnt(0)" ::: "memory");
    __builtin_amdgcn_sched_barrier(0);
    short8 bo0 = *(const short8*)&s_o1[lr][lg*8];
    short8 bo1 = *(const short8*)&s_o1[lr][32 + lg*8];
    f32x4 e[3];
    #pragma unroll
    for (int mt = 0; mt < 3; ++mt) e[mt] = *(const f32x4*)&s_eb2[mt*16 + lg*4];
    #pragma unroll
    for (int mt = 0; mt < 3; ++mt) {
      e[mt] = __builtin_amdgcn_mfma_f32_16x16x32_bf16(we2[mt][0], bo0, e[mt], 0, 0, 0);
      e[mt] = __builtin_amdgcn_mfma_f32_16x16x32_bf16(we2[mt][1], bo1, e[mt], 0, 0, 0);
    }
    #pragma unroll
    for (int mt = 0; mt < 3; ++mt) {
      *(u32*)&s_xh[pp][lr][mt*16 + lg*4]     = pk2(e[mt][0], e[mt][1]);
      *(u32*)&s_xh[pp][lr][mt*16 + lg*4 + 2] = pk2(e[mt][2], e[mt][3]);
    }
  };
  auto load_xs = [&](int t, float4& a0, float4& b0_, float4& a1, float4& b1_) {
    a0 = *(const float4*)(xrow + (size_t)t*SDIM + lg*8);
    b0_= *(const float4*)(xrow + (size_t)t*SDIM + lg*8 + 4);
    if (lg < 2) {
      a1 = *(const float4*)(xrow + (size_t)t*SDIM + 32 + lg*8);
      b1_= *(const float4*)(xrow + (size_t)t*SDIM + 32 + lg*8 + 4);
    }
  };

  float4 zf4 = make_float4(0.f, 0.f, 0.f, 0.f);
  float4 xn0a = zf4, xn0b = zf4, xn1a = zf4, xn1b = zf4;
  if (w == 7) {
    float4 c0a = zf4, c0b = zf4, c1a = zf4, c1b = zf4;
    load_xs(0, c0a, c0b, c1a, c1b);
    enc_step(pack8(c0a, c0b), pack8(c1a, c1b), 0);
    load_xs(1, xn0a, xn0b, xn1a, xn1b);
  }
  float c_reg[4] = {0.f, 0.f, 0.f, 0.f};
  __syncthreads();

  for (int st = 0; st < NSTEP; ++st) {
    const int p  = st & 1;
    const int p2 = p ^ 1;

    short8 bh[6];
    #pragma unroll
    for (int kt = 0; kt < 6; ++kt)
      bh[kt] = *(const short8*)&s_xh[p][lr][kt*32 + lg*8];

    f32x4 acc[4];
    #pragma unroll
    for (int q = 0; q < 4; ++q) acc[q] = *(const f32x4*)&s_bias[(w + 8*q)*16 + lg*4];
    #pragma unroll
    for (int kt = 0; kt < 6; ++kt)
      #pragma unroll
      for (int q = 0; q < 4; ++q)
        acc[q] = __builtin_amdgcn_mfma_f32_16x16x32_bf16(wf[q][kt], bh[kt], acc[q], 0, 0, 0);

    f32x4 pa = *(const f32x4*)&s_pp[p][lr][0];
    f32x4 pb = *(const f32x4*)&s_pp[p][lr][4];
    float pp_s = ((pa[0]+pa[1]) + (pa[2]+pa[3])) + ((pb[0]+pb[1]) + (pb[2]+pb[3]));
    float pred_prev = pp_s + ob;
    if (st == 0) pred_prev = 0.f;
    if (st > 0 && l < 16 && (l >> 1) == w)
      out[(b0 + l)*NSTEP + (st - 1)] = pred_prev;

    float tf = 0.f;
    if (st < twc) tf = yrow[st];
    const float flow = (st < twc) ? tf : pred_prev;

    if (w == 7) {
      short8 bx0 = pack8(xn0a, xn0b);
      short8 bx1 = pack8(xn1a, xn1b);
      const int tt = (st + 2 < TFULL) ? (st + 2) : (TFULL - 1);
      load_xs(tt, xn0a, xn0b, xn1a, xn1b);
      __builtin_amdgcn_s_setprio(1);
      enc_step(bx0, bx1, p2);
      __builtin_amdgcn_s_setprio(0);
    }

    float hv[4];
    float hsum = 0.f;
    #pragma unroll
    for (int r = 0; r < 4; ++r) {
      float g_i = acc[0][r] + wfl[0][r]*flow;
      float g_f = acc[1][r] + wfl[1][r]*flow;
      float g_g = acc[2][r] + wfl[2][r]*flow;
      float g_o = acc[3][r] + wfl[3][r]*flow;
      float iv = sigm(g_i);
      float fv = sigm(g_f);
      float gv = tanh_f(g_g);
      float ov = sigm(g_o);
      float c  = fv*c_reg[r] + iv*gv;
      c_reg[r] = c;
      hv[r] = ov*tanh_f(c);
      hsum += hv[r]*owv[r];
    }
    *(u32*)&s_xh[p2][lr][48 + w*16 + lg*4]     = pk2(hv[0], hv[1]);
    *(u32*)&s_xh[p2][lr][48 + w*16 + lg*4 + 2] = pk2(hv[2], hv[3]);
    hsum += __shfl_xor(hsum, 16);
    hsum += __shfl_xor(hsum, 32);
    if (l < 16) s_pp[p2][l][w] = hsum;
    __syncthreads();
  }

  f32x4 pa = *(const f32x4*)&s_pp[NSTEP & 1][lr][0];
  f32x4 pb = *(const f32x4*)&s_pp[NSTEP & 1][lr][4];
  float pp_s = ((pa[0]+pa[1]) + (pa[2]+pa[3])) + ((pb[0]+pb[1]) + (pb[2]+pb[3]));
  if (l < 16 && (l >> 1) == w)
    out[(b0 + l)*NSTEP + (NSTEP - 1)] = pp_s + ob;
}

extern "C" void kernel_launch(void* const* d_in, const int* in_sizes, int n_in,
                              void* d_out, int out_size, void* d_ws, size_t ws_size,
                              hipStream_t stream) {
  const float* y_flow    = (const float*)d_in[0];
  const float* x_statics = (const float*)d_in[1];
  const int*   twin      = (const int*)  d_in[2];
  const float* enc_w1    = (const float*)d_in[3];
  const float* enc_b1    = (const float*)d_in[4];
  const float* enc_w2    = (const float*)d_in[5];
  const float* enc_b2    = (const float*)d_in[6];
  const float* w_ih      = (const float*)d_in[7];
  const float* w_hh      = (const float*)d_in[8];
  const float* b_ih      = (const float*)d_in[9];
  const float* b_hh      = (const float*)d_in[10];
  const float* out_w     = (const float*)d_in[11];
  const float* out_b     = (const float*)d_in[12];
  float* out = (float*)d_out;

  char* ws = (char*)d_ws;
  u16*   frags   = (u16*)ws;
  float* bias    = (float*)(ws + BIAS_BYTE_OFF);
  u16*   enc_buf = (u16*)(ws + ENC_BYTE_OFF);

  const int pre = (ws_size >= (size_t)ENC_BYTE_OFF + ENC_BYTES) ? 1 : 0;

  setup_weights<<<128, 256, 0, stream>>>(w_ih, w_hh, b_ih, b_hh, enc_w1, enc_w2,
                                         frags, bias, pre);
  if (pre) {
    enc_pre<<<4096*8, 256, 0, stream>>>(x_statics, enc_b1, enc_b2, frags, enc_buf);
    lstm_pre<<<256, 512, 0, stream>>>(y_flow, twin, out_w, out_b,
                                      frags, enc_buf, out);
  } else {
    lstm_fb<<<256, 512, 0, stream>>>(y_flow, x_statics, twin,
                                     enc_b1, enc_b2, out_w, out_b, w_ih,
                                     frags, bias, out);
  }
}

// Round 13
// 925.831 us; speedup vs baseline: 1.2601x; 1.1124x over previous
//
#include <hip/hip_runtime.h>
#include <hip/hip_bf16.h>

#define HID 128
#define SDIM 48
#define NSTEP 511
#define TFULL 512
#define ROWS 16
#define XHS 200            // fallback xh stride (u16)
#define HSTR 136           // h stride (u16): 272B, 16B-aligned
#define O1S 88
#define WENC_OFF 98304
#define BIAS_BYTE_OFF 208896
#define ENC_BYTE_OFF 211200                    // 256B-aligned
#define ENC_BYTES (4096ULL*TFULL*SDIM*2ULL)    // [b][512][48] bf16 = 201.3 MB

typedef unsigned short u16;
typedef unsigned int   u32;
typedef __attribute__((ext_vector_type(8))) short short8;
typedef __attribute__((ext_vector_type(4))) float f32x4;
typedef __attribute__((ext_vector_type(4))) u32   u32x4;

__device__ __forceinline__ float frcp(float x)  { return __builtin_amdgcn_rcpf(x); }
__device__ __forceinline__ float sigm(float x)  { return frcp(1.0f + __expf(-x)); }
__device__ __forceinline__ float tanh_f(float x){ return 1.0f - 2.0f*frcp(1.0f + __expf(2.0f*x)); }
__device__ __forceinline__ u16 f2bf(float f) {
  __hip_bfloat16 h = __float2bfloat16(f);
  return *reinterpret_cast<u16*>(&h);
}
__device__ __forceinline__ u32 pk2(float a, float b) {
  return (u32)f2bf(a) | ((u32)f2bf(b) << 16);
}
// single-instruction packed f32->2xbf16 (RNE), gfx950
__device__ __forceinline__ u32 cvtpk(float lo, float hi) {
  u32 r;
  asm("v_cvt_pk_bf16_f32 %0, %1, %2" : "=v"(r) : "v"(lo), "v"(hi));
  return r;
}
// opaque register pin: value appears modified -> compiler cannot rematerialize
// the originating load; must keep it live in VGPRs across the loop.
__device__ __forceinline__ void pin8(short8 &x) {
  u32x4 t = __builtin_bit_cast(u32x4, x);
  asm volatile("" : "+v"(t[0]), "+v"(t[1]), "+v"(t[2]), "+v"(t[3]));
  x = __builtin_bit_cast(short8, t);
}
__device__ __forceinline__ void pin4f(f32x4 &x) {
  asm volatile("" : "+v"(x[0]), "+v"(x[1]), "+v"(x[2]), "+v"(x[3]));
}
__device__ __forceinline__ short8 pack8(float4 a, float4 b) {
  short8 r;
  r[0]=(short)f2bf(a.x); r[1]=(short)f2bf(a.y); r[2]=(short)f2bf(a.z); r[3]=(short)f2bf(a.w);
  r[4]=(short)f2bf(b.x); r[5]=(short)f2bf(b.y); r[6]=(short)f2bf(b.z); r[7]=(short)f2bf(b.w);
  return r;
}

// hfirst=1 (pre path):  K = [0..127]=h, [128..175]=enc, [176]=flow(w_ih col0),
//                       [177]=bias col (unused when bias rides in C; B supplies 0)
// hfirst=0 (fallback):  K = [0..47]=enc, [48..175]=h, [176..191]=0 (flow via rank-1)
__global__ void setup_weights(const float* __restrict__ w_ih, const float* __restrict__ w_hh,
                              const float* __restrict__ b_ih, const float* __restrict__ b_hh,
                              const float* __restrict__ enc_w1, const float* __restrict__ enc_w2,
                              u16* __restrict__ frags, float* __restrict__ bias, int hfirst) {
  int stride = gridDim.x * blockDim.x;
  int i0 = blockIdx.x * blockDim.x + threadIdx.x;
  for (int idx = i0; idx < 32*6*64*8; idx += stride) {
    int j  = idx & 7;
    int l  = (idx >> 3) & 63;
    int kt = (idx >> 9) % 6;
    int mt = (idx >> 9) / 6;
    int gr = mt*16 + (l & 15);
    int k  = kt*32 + (l >> 4)*8 + j;
    float v = 0.f;
    if (hfirst) {
      if (k < HID)        v = w_hh[gr*HID + k];
      else if (k < 176)   v = w_ih[gr*49 + 1 + (k - HID)];
      else if (k == 176)  v = w_ih[gr*49 + 0];             // flow column
      else if (k == 177)  v = b_ih[gr] + b_hh[gr];         // bias column (B gives 0 here)
    } else {
      if (k < 48)         v = w_ih[gr*49 + 1 + k];
      else if (k < 176)   v = w_hh[gr*HID + (k - 48)];
    }
    frags[idx] = f2bf(v);
  }
  for (int idx = i0; idx < 2*3*2*64*8; idx += stride) {
    int j   = idx & 7;
    int l   = (idx >> 3) & 63;
    int kt  = (idx >> 9) & 1;
    int mt  = (idx >> 10) % 3;
    int lyr = (idx >> 10) / 3;
    int row = mt*16 + (l & 15);
    int k   = kt*32 + (l >> 4)*8 + j;
    float v = 0.f;
    if (k < SDIM) v = (lyr ? enc_w2 : enc_w1)[row*SDIM + k];
    frags[WENC_OFF + idx] = f2bf(v);
  }
  for (int idx = i0; idx < 512; idx += stride)
    bias[idx] = b_ih[idx] + b_hh[idx];
}

// ---------------- kernel 2: precompute enc(b,t) for all t (massively parallel) --------
__global__ __launch_bounds__(256)
void enc_pre(const float* __restrict__ x_statics,
             const float* __restrict__ enc_b1, const float* __restrict__ enc_b2,
             const u16* __restrict__ frags, u16* __restrict__ enc_buf) {
  __shared__ __attribute__((aligned(16))) u16 s_o1[4][ROWS][O1S];
  const int tid = threadIdx.x;
  const int w  = tid >> 6;
  const int l  = tid & 63;
  const int lr = l & 15;
  const int lg = l >> 4;
  const int b     = blockIdx.x >> 3;
  const int chunk = blockIdx.x & 7;
  const int t = chunk*64 + w*16 + lr;

  short8 we1[3][2], we2[3][2];
  f32x4 a[3], e[3];
  #pragma unroll
  for (int mt = 0; mt < 3; ++mt) {
    #pragma unroll
    for (int kt = 0; kt < 2; ++kt) {
      we1[mt][kt] = *(const short8*)(frags + WENC_OFF + (((0*3 + mt)*2 + kt)*64 + l)*8);
      we2[mt][kt] = *(const short8*)(frags + WENC_OFF + (((1*3 + mt)*2 + kt)*64 + l)*8);
    }
    a[mt] = *(const f32x4*)&enc_b1[mt*16 + lg*4];
    e[mt] = *(const f32x4*)&enc_b2[mt*16 + lg*4];
  }

  *(unsigned long long*)&s_o1[w][l & 15][48 + (l >> 4)*4] = 0ULL;

  const float* xbase = x_statics + ((size_t)b*TFULL + t)*SDIM;
  float4 zf4 = make_float4(0.f,0.f,0.f,0.f);
  float4 c0a = *(const float4*)(xbase + lg*8);
  float4 c0b = *(const float4*)(xbase + lg*8 + 4);
  float4 c1a = zf4, c1b = zf4;
  if (lg < 2) {
    c1a = *(const float4*)(xbase + 32 + lg*8);
    c1b = *(const float4*)(xbase + 32 + lg*8 + 4);
  }
  short8 bx0 = pack8(c0a, c0b);
  short8 bx1 = pack8(c1a, c1b);

  #pragma unroll
  for (int mt = 0; mt < 3; ++mt) {
    a[mt] = __builtin_amdgcn_mfma_f32_16x16x32_bf16(we1[mt][0], bx0, a[mt], 0, 0, 0);
    a[mt] = __builtin_amdgcn_mfma_f32_16x16x32_bf16(we1[mt][1], bx1, a[mt], 0, 0, 0);
  }
  #pragma unroll
  for (int mt = 0; mt < 3; ++mt) {
    u32 lo = pk2(fmaxf(a[mt][0],0.f), fmaxf(a[mt][1],0.f));
    u32 hi = pk2(fmaxf(a[mt][2],0.f), fmaxf(a[mt][3],0.f));
    *(uint2*)&s_o1[w][lr][mt*16 + lg*4] = make_uint2(lo, hi);
  }
  asm volatile("s_waitcnt lgkmcnt(0)" ::: "memory");
  __builtin_amdgcn_sched_barrier(0);
  short8 bo0 = *(const short8*)&s_o1[w][lr][lg*8];
  short8 bo1 = *(const short8*)&s_o1[w][lr][32 + lg*8];
  #pragma unroll
  for (int mt = 0; mt < 3; ++mt) {
    e[mt] = __builtin_amdgcn_mfma_f32_16x16x32_bf16(we2[mt][0], bo0, e[mt], 0, 0, 0);
    e[mt] = __builtin_amdgcn_mfma_f32_16x16x32_bf16(we2[mt][1], bo1, e[mt], 0, 0, 0);
  }
  if (t < NSTEP) {
    u16* dst = enc_buf + ((size_t)b*TFULL + t)*SDIM;
    #pragma unroll
    for (int mt = 0; mt < 3; ++mt)
      *(uint2*)(dst + mt*16 + lg*4) = make_uint2(pk2(e[mt][0], e[mt][1]), pk2(e[mt][2], e[mt][3]));
  }
}

// ---------------- kernel 3: LSTM loop — R8 structure + PINNED weight registers -------
// 256 blocks x 512 threads (8 waves, 2/SIMD, 256-VGPR budget). Wave w owns gate
// M-tiles {w,w+8,w+16,w+24}; i/f/g/o in-lane. Weights pinned in VGPRs (asm pin
// prevents rematerialization -> no L2 reloads in the loop). Bias rides in the
// first MFMA's C-operand; flow enters via K column 176 (one cvt_pk patch).
__global__ __launch_bounds__(512, 2)
void lstm_pre(const float* __restrict__ y_flow,
              const int* __restrict__ twin_p,
              const float* __restrict__ out_w, const float* __restrict__ out_b,
              const float* __restrict__ bias,
              const u16* __restrict__ frags,
              const u16* __restrict__ enc_buf,
              float* __restrict__ out) {
  __shared__ __attribute__((aligned(16))) u16   s_h[2][ROWS][HSTR];
  __shared__ __attribute__((aligned(16))) float s_pp[2][8][ROWS];

  const int tid = threadIdx.x;
  const int blk = blockIdx.x;
  const int w  = tid >> 6;
  const int l  = tid & 63;
  const int lr = l & 15;
  const int lg = l >> 4;
  const size_t b0 = (size_t)blk * ROWS;

  // weight fragments -> VGPRs, then PIN (cannot be rematerialized/demoted)
  short8 wf[4][6];
  #pragma unroll
  for (int q = 0; q < 4; ++q)
    #pragma unroll
    for (int kt = 0; kt < 6; ++kt)
      wf[q][kt] = *(const short8*)(frags + (((w + 8*q)*6 + kt)*64 + l)*8);
  #pragma unroll
  for (int q = 0; q < 4; ++q)
    #pragma unroll
    for (int kt = 0; kt < 6; ++kt)
      pin8(wf[q][kt]);

  // gate bias (C-operand of first MFMA) — pinned too
  f32x4 bgv[4];
  #pragma unroll
  for (int q = 0; q < 4; ++q) {
    bgv[q] = *(const f32x4*)&bias[(w + 8*q)*16 + lg*4];
    pin4f(bgv[q]);
  }

  float owv[4];
  #pragma unroll
  for (int r = 0; r < 4; ++r) owv[r] = out_w[w*16 + lg*4 + r];
  const float ob  = out_b[0];
  const int   twc = twin_p[0] - 1;   // teacher iff t < twc

  const u16*   erow = enc_buf + (size_t)(b0 + lr)*TFULL*SDIM;
  const float* yrow = y_flow  + (size_t)(b0 + lr)*TFULL;

  // prefetch enc(0)
  short8 encA = *(const short8*)(erow + lg*8);
  short8 encB = {};
  if (lg < 2) encB = *(const short8*)(erow + 32 + lg*8);

  for (int i = tid; i < 2*ROWS*HSTR; i += 512) ((u16*)s_h)[i] = 0;
  for (int i = tid; i < 2*8*ROWS;   i += 512) ((float*)s_pp)[i] = 0.f;
  float c_reg[4] = {0.f, 0.f, 0.f, 0.f};
  __syncthreads();

  for (int st = 0; st < NSTEP; ++st) {
    const int p  = st & 1;
    const int p2 = p ^ 1;

    // B fragments (h from ping-pong, enc from prefetch regs)
    short8 bh[6];
    #pragma unroll
    for (int kt = 0; kt < 4; ++kt)
      bh[kt] = *(const short8*)&s_h[p][lr][kt*32 + lg*8];
    bh[4] = encA;

    // teacher flow + pred(st-1)
    float tf = 0.f;
    if (st < twc) tf = yrow[st];
    float pp01 = s_pp[p][0][lr] + s_pp[p][1][lr];
    float pp23 = s_pp[p][2][lr] + s_pp[p][3][lr];
    float pp45 = s_pp[p][4][lr] + s_pp[p][5][lr];
    float pp67 = s_pp[p][6][lr] + s_pp[p][7][lr];
    float pred_prev = ((pp01 + pp23) + (pp45 + pp67)) + ob;
    if (st == 0) pred_prev = 0.f;
    if (st > 0 && l < 16 && (l >> 1) == w)
      out[(b0 + l)*NSTEP + (st - 1)] = pred_prev;
    const float flow = (st < twc) ? tf : pred_prev;

    // kt5: enc cols 32..47 (lg<2); lg==2 word0 = {flow@k176, 0@k177}
    u32x4 bv = __builtin_bit_cast(u32x4, encB);
    u32 fw = cvtpk(flow, 0.0f);
    bv[0] = (lg == 2) ? fw : bv[0];
    bh[5] = __builtin_bit_cast(short8, bv);

    // prefetch enc(st+1); row 511 garbage, never consumed
    const int tt = (st + 1) & 511;
    encA = *(const short8*)(erow + (size_t)tt*SDIM + lg*8);
    encB = (short8){};
    if (lg < 2) encB = *(const short8*)(erow + (size_t)tt*SDIM + 32 + lg*8);

    // gates: first MFMA carries bias in C; then 5 more accumulating
    f32x4 acc[4];
    #pragma unroll
    for (int q = 0; q < 4; ++q)
      acc[q] = __builtin_amdgcn_mfma_f32_16x16x32_bf16(wf[q][0], bh[0], bgv[q], 0, 0, 0);
    #pragma unroll
    for (int kt = 1; kt < 6; ++kt)
      #pragma unroll
      for (int q = 0; q < 4; ++q)
        acc[q] = __builtin_amdgcn_mfma_f32_16x16x32_bf16(wf[q][kt], bh[kt], acc[q], 0, 0, 0);

    // LSTM cell (bias + flow already inside acc)
    float hv[4];
    float hsum = 0.f;
    #pragma unroll
    for (int r = 0; r < 4; ++r) {
      float iv = sigm(acc[0][r]);
      float fv = sigm(acc[1][r]);
      float gv = tanh_f(acc[2][r]);
      float ov = sigm(acc[3][r]);
      float c  = fv*c_reg[r] + iv*gv;
      c_reg[r] = c;
      hv[r] = ov*tanh_f(c);
      hsum += hv[r]*owv[r];
    }
    *(uint2*)&s_h[p2][lr][w*16 + lg*4] =
        make_uint2(cvtpk(hv[0], hv[1]), cvtpk(hv[2], hv[3]));
    hsum += __shfl_xor(hsum, 16);
    hsum += __shfl_xor(hsum, 32);
    if (l < 16) s_pp[p2][w][l] = hsum;
    __syncthreads();
  }

  // epilogue: pred(NSTEP-1)
  const int pe = NSTEP & 1;
  float pp01 = s_pp[pe][0][lr] + s_pp[pe][1][lr];
  float pp23 = s_pp[pe][2][lr] + s_pp[pe][3][lr];
  float pp45 = s_pp[pe][4][lr] + s_pp[pe][5][lr];
  float pp67 = s_pp[pe][6][lr] + s_pp[pe][7][lr];
  if (l < 16 && (l >> 1) == w)
    out[(b0 + l)*NSTEP + (NSTEP - 1)] = ((pp01 + pp23) + (pp45 + pp67)) + ob;
}

// ---------------- fallback: R5 kernel verbatim (wave-7 inline encoder) ---------------
__global__ __launch_bounds__(512, 2)
void lstm_fb(const float* __restrict__ y_flow,
             const float* __restrict__ x_statics,
             const int* __restrict__ twin_p,
             const float* __restrict__ enc_b1, const float* __restrict__ enc_b2,
             const float* __restrict__ out_w, const float* __restrict__ out_b,
             const float* __restrict__ w_ih,
             const u16* __restrict__ frags, const float* __restrict__ bias,
             float* __restrict__ out) {
  __shared__ __attribute__((aligned(16))) u16   s_xh[2][ROWS][XHS];
  __shared__ __attribute__((aligned(16))) u16   s_o1[ROWS][O1S];
  __shared__ __attribute__((aligned(16))) float s_pp[2][ROWS][8];
  __shared__ __attribute__((aligned(16))) float s_bias[512];
  __shared__ __attribute__((aligned(16))) float s_eb1[SDIM];
  __shared__ __attribute__((aligned(16))) float s_eb2[SDIM];

  const int tid = threadIdx.x;
  const int blk = blockIdx.x;
  const int w  = tid >> 6;
  const int l  = tid & 63;
  const int lr = l & 15;
  const int lg = l >> 4;
  const size_t b0 = (size_t)blk * ROWS;

  short8 wf[4][6];
  #pragma unroll
  for (int q = 0; q < 4; ++q)
    #pragma unroll
    for (int kt = 0; kt < 6; ++kt)
      wf[q][kt] = *(const short8*)(frags + (((w + 8*q)*6 + kt)*64 + l)*8);

  float wfl[4][4];
  #pragma unroll
  for (int q = 0; q < 4; ++q)
    #pragma unroll
    for (int r = 0; r < 4; ++r)
      wfl[q][r] = w_ih[((w + 8*q)*16 + lg*4 + r)*49];

  short8 we1[3][2], we2[3][2];
  if (w == 7) {
    #pragma unroll
    for (int mt = 0; mt < 3; ++mt)
      #pragma unroll
      for (int kt = 0; kt < 2; ++kt) {
        we1[mt][kt] = *(const short8*)(frags + WENC_OFF + (((0*3 + mt)*2 + kt)*64 + l)*8);
        we2[mt][kt] = *(const short8*)(frags + WENC_OFF + (((1*3 + mt)*2 + kt)*64 + l)*8);
      }
  }

  float owv[4];
  #pragma unroll
  for (int r = 0; r < 4; ++r) owv[r] = out_w[w*16 + lg*4 + r];
  const float ob  = out_b[0];
  const int   twc = twin_p[0] - 1;

  for (int i = tid; i < 2*ROWS*XHS; i += 512) ((u16*)s_xh)[i] = 0;
  for (int i = tid; i < ROWS*O1S;  i += 512) ((u16*)s_o1)[i] = 0;
  for (int i = tid; i < 2*ROWS*8;  i += 512) ((float*)s_pp)[i] = 0.f;
  s_bias[tid] = bias[tid];
  if (tid < SDIM) { s_eb1[tid] = enc_b1[tid]; s_eb2[tid] = enc_b2[tid]; }
  __syncthreads();

  const float* xrow = x_statics + (size_t)(b0 + lr)*TFULL*SDIM;
  const float* yrow = y_flow    + (size_t)(b0 + lr)*TFULL;

  auto enc_step = [&](short8 bx0, short8 bx1, int pp) {
    f32x4 a[3];
    #pragma unroll
    for (int mt = 0; mt < 3; ++mt) a[mt] = *(const f32x4*)&s_eb1[mt*16 + lg*4];
    #pragma unroll
    for (int mt = 0; mt < 3; ++mt) {
      a[mt] = __builtin_amdgcn_mfma_f32_16x16x32_bf16(we1[mt][0], bx0, a[mt], 0, 0, 0);
      a[mt] = __builtin_amdgcn_mfma_f32_16x16x32_bf16(we1[mt][1], bx1, a[mt], 0, 0, 0);
    }
    #pragma unroll
    for (int mt = 0; mt < 3; ++mt) {
      *(u32*)&s_o1[lr][mt*16 + lg*4]     = pk2(fmaxf(a[mt][0],0.f), fmaxf(a[mt][1],0.f));
      *(u32*)&s_o1[lr][mt*16 + lg*4 + 2] = pk2(fmaxf(a[mt][2],0.f), fmaxf(a[mt][3],0.f));
    }
    asm volatile("s_waitcnt lgkmcnt(0)" ::: "memory");
    __builtin_amdgcn_sched_barrier(0);
    short8 bo0 = *(const short8*)&s_o1[lr][lg*8];
    short8 bo1 = *(const short8*)&s_o1[lr][32 + lg*8];
    f32x4 e[3];
    #pragma unroll
    for (int mt = 0; mt < 3; ++mt) e[mt] = *(const f32x4*)&s_eb2[mt*16 + lg*4];
    #pragma unroll
    for (int mt = 0; mt < 3; ++mt) {
      e[mt] = __builtin_amdgcn_mfma_f32_16x16x32_bf16(we2[mt][0], bo0, e[mt], 0, 0, 0);
      e[mt] = __builtin_amdgcn_mfma_f32_16x16x32_bf16(we2[mt][1], bo1, e[mt], 0, 0, 0);
    }
    #pragma unroll
    for (int mt = 0; mt < 3; ++mt) {
      *(u32*)&s_xh[pp][lr][mt*16 + lg*4]     = pk2(e[mt][0], e[mt][1]);
      *(u32*)&s_xh[pp][lr][mt*16 + lg*4 + 2] = pk2(e[mt][2], e[mt][3]);
    }
  };
  auto load_xs = [&](int t, float4& a0, float4& b0_, float4& a1, float4& b1_) {
    a0 = *(const float4*)(xrow + (size_t)t*SDIM + lg*8);
    b0_= *(const float4*)(xrow + (size_t)t*SDIM + lg*8 + 4);
    if (lg < 2) {
      a1 = *(const float4*)(xrow + (size_t)t*SDIM + 32 + lg*8);
      b1_= *(const float4*)(xrow + (size_t)t*SDIM + 32 + lg*8 + 4);
    }
  };

  float4 zf4 = make_float4(0.f, 0.f, 0.f, 0.f);
  float4 xn0a = zf4, xn0b = zf4, xn1a = zf4, xn1b = zf4;
  if (w == 7) {
    float4 c0a = zf4, c0b = zf4, c1a = zf4, c1b = zf4;
    load_xs(0, c0a, c0b, c1a, c1b);
    enc_step(pack8(c0a, c0b), pack8(c1a, c1b), 0);
    load_xs(1, xn0a, xn0b, xn1a, xn1b);
  }
  float c_reg[4] = {0.f, 0.f, 0.f, 0.f};
  __syncthreads();

  for (int st = 0; st < NSTEP; ++st) {
    const int p  = st & 1;
    const int p2 = p ^ 1;

    short8 bh[6];
    #pragma unroll
    for (int kt = 0; kt < 6; ++kt)
      bh[kt] = *(const short8*)&s_xh[p][lr][kt*32 + lg*8];

    f32x4 acc[4];
    #pragma unroll
    for (int q = 0; q < 4; ++q) acc[q] = *(const f32x4*)&s_bias[(w + 8*q)*16 + lg*4];
    #pragma unroll
    for (int kt = 0; kt < 6; ++kt)
      #pragma unroll
      for (int q = 0; q < 4; ++q)
        acc[q] = __builtin_amdgcn_mfma_f32_16x16x32_bf16(wf[q][kt], bh[kt], acc[q], 0, 0, 0);

    f32x4 pa = *(const f32x4*)&s_pp[p][lr][0];
    f32x4 pb = *(const f32x4*)&s_pp[p][lr][4];
    float pp_s = ((pa[0]+pa[1]) + (pa[2]+pa[3])) + ((pb[0]+pb[1]) + (pb[2]+pb[3]));
    float pred_prev = pp_s + ob;
    if (st == 0) pred_prev = 0.f;
    if (st > 0 && l < 16 && (l >> 1) == w)
      out[(b0 + l)*NSTEP + (st - 1)] = pred_prev;

    float tf = 0.f;
    if (st < twc) tf = yrow[st];
    const float flow = (st < twc) ? tf : pred_prev;

    if (w == 7) {
      short8 bx0 = pack8(xn0a, xn0b);
      short8 bx1 = pack8(xn1a, xn1b);
      const int tt = (st + 2 < TFULL) ? (st + 2) : (TFULL - 1);
      load_xs(tt, xn0a, xn0b, xn1a, xn1b);
      __builtin_amdgcn_s_setprio(1);
      enc_step(bx0, bx1, p2);
      __builtin_amdgcn_s_setprio(0);
    }

    float hv[4];
    float hsum = 0.f;
    #pragma unroll
    for (int r = 0; r < 4; ++r) {
      float g_i = acc[0][r] + wfl[0][r]*flow;
      float g_f = acc[1][r] + wfl[1][r]*flow;
      float g_g = acc[2][r] + wfl[2][r]*flow;
      float g_o = acc[3][r] + wfl[3][r]*flow;
      float iv = sigm(g_i);
      float fv = sigm(g_f);
      float gv = tanh_f(g_g);
      float ov = sigm(g_o);
      float c  = fv*c_reg[r] + iv*gv;
      c_reg[r] = c;
      hv[r] = ov*tanh_f(c);
      hsum += hv[r]*owv[r];
    }
    *(u32*)&s_xh[p2][lr][48 + w*16 + lg*4]     = pk2(hv[0], hv[1]);
    *(u32*)&s_xh[p2][lr][48 + w*16 + lg*4 + 2] = pk2(hv[2], hv[3]);
    hsum += __shfl_xor(hsum, 16);
    hsum += __shfl_xor(hsum, 32);
    if (l < 16) s_pp[p2][l][w] = hsum;
    __syncthreads();
  }

  f32x4 pa = *(const f32x4*)&s_pp[NSTEP & 1][lr][0];
  f32x4 pb = *(const f32x4*)&s_pp[NSTEP & 1][lr][4];
  float pp_s = ((pa[0]+pa[1]) + (pa[2]+pa[3])) + ((pb[0]+pb[1]) + (pb[2]+pb[3]));
  if (l < 16 && (l >> 1) == w)
    out[(b0 + l)*NSTEP + (NSTEP - 1)] = pp_s + ob;
}

extern "C" void kernel_launch(void* const* d_in, const int* in_sizes, int n_in,
                              void* d_out, int out_size, void* d_ws, size_t ws_size,
                              hipStream_t stream) {
  const float* y_flow    = (const float*)d_in[0];
  const float* x_statics = (const float*)d_in[1];
  const int*   twin      = (const int*)  d_in[2];
  const float* enc_w1    = (const float*)d_in[3];
  const float* enc_b1    = (const float*)d_in[4];
  const float* enc_w2    = (const float*)d_in[5];
  const float* enc_b2    = (const float*)d_in[6];
  const float* w_ih      = (const float*)d_in[7];
  const float* w_hh      = (const float*)d_in[8];
  const float* b_ih      = (const float*)d_in[9];
  const float* b_hh      = (const float*)d_in[10];
  const float* out_w     = (const float*)d_in[11];
  const float* out_b     = (const float*)d_in[12];
  float* out = (float*)d_out;

  char* ws = (char*)d_ws;
  u16*   frags   = (u16*)ws;
  float* bias    = (float*)(ws + BIAS_BYTE_OFF);
  u16*   enc_buf = (u16*)(ws + ENC_BYTE_OFF);

  const int pre = (ws_size >= (size_t)ENC_BYTE_OFF + ENC_BYTES) ? 1 : 0;

  setup_weights<<<128, 256, 0, stream>>>(w_ih, w_hh, b_ih, b_hh, enc_w1, enc_w2,
                                         frags, bias, pre);
  if (pre) {
    enc_pre<<<4096*8, 256, 0, stream>>>(x_statics, enc_b1, enc_b2, frags, enc_buf);
    lstm_pre<<<256, 512, 0, stream>>>(y_flow, twin, out_w, out_b, bias,
                                      frags, enc_buf, out);
  } else {
    lstm_fb<<<256, 512, 0, stream>>>(y_flow, x_statics, twin,
                                     enc_b1, enc_b2, out_w, out_b, w_ih,
                                     frags, bias, out);
  }
}